// Round 1
// baseline (743.532 us; speedup 1.0000x reference)
//
#include <hip/hip_runtime.h>
#include <hip/hip_bf16.h>

#define BN 8
#define NN 2000
#define LL 128
#define EE 2048
#define DIN 258
#define KPAD 264
#define NROWS (BN*NN)
#define PENALTY_V 10.0f

// ---------------- Kernel A: Wc = W1@W2 (KPAD x 128), bc = b1@W2 + b2 ----------------
__global__ __launch_bounds__(256) void kA(const float* __restrict__ W1,
                                          const float* __restrict__ b1,
                                          const float* __restrict__ W2,
                                          const float* __restrict__ b2,
                                          float* __restrict__ Wc,
                                          float* __restrict__ bc) {
    __shared__ float As2[8][64];
    const int t = threadIdx.x;
    const int j = t & 127;
    const int half = t >> 7;          // 0 or 1
    const int k0 = blockIdx.x * 8;    // 33 blocks cover rows 0..263
    float acc[4] = {0.f, 0.f, 0.f, 0.f};
    for (int ec = 0; ec < EE; ec += 64) {
        // stage A'[k0..k0+7][ec..ec+63]; A' = [W1; b1; zeros]
        #pragma unroll
        for (int q = 0; q < 2; ++q) {
            int linear = q * 256 + t;
            int r8 = linear >> 6;
            int e  = linear & 63;
            int k  = k0 + r8;
            float v;
            if (k < DIN)       v = W1[k * EE + ec + e];
            else if (k == DIN) v = b1[ec + e];
            else               v = 0.0f;
            As2[r8][e] = v;
        }
        __syncthreads();
        #pragma unroll 8
        for (int e = 0; e < 64; ++e) {
            float w = W2[(ec + e) * LL + j];
            #pragma unroll
            for (int rr = 0; rr < 4; ++rr)
                acc[rr] += As2[half * 4 + rr][e] * w;
        }
        __syncthreads();
    }
    #pragma unroll
    for (int rr = 0; rr < 4; ++rr) {
        int k = k0 + half * 4 + rr;
        if (k == DIN) {
            bc[j] = acc[rr] + b2[j];
            Wc[k * LL + j] = 0.0f;      // padded row must be zero (ws is poisoned)
        } else if (k < KPAD) {
            Wc[k * LL + j] = (k < DIN) ? acc[rr] : 0.0f;
        }
    }
}

// ---------------- Kernel B: per-row top-128 (sorted, tie=lower idx) + build x_in ----------------
__global__ __launch_bounds__(256) void kB(const float* __restrict__ dist,
                                          const float* __restrict__ theta,
                                          const float* __restrict__ f0,
                                          const float* __restrict__ f1,
                                          float* __restrict__ xin,
                                          int*   __restrict__ gidx) {
    __shared__ unsigned int sbits[NN];              // 8000 B (reused for theta row later)
    __shared__ unsigned long long cand[512];        // 4096 B
    __shared__ unsigned int hist[256];              // 1024 B
    __shared__ unsigned int s_sel[4];               // [0]=rank r, [1]=prefix, [2]=ncand
    const int t = threadIdx.x;
    const int row = blockIdx.x;

    // Phase 1: load dist row bits (positive floats -> monotone uint bits)
    {
        const uint4* drow4 = (const uint4*)(dist + (size_t)row * NN);
        uint4* sbits4 = (uint4*)sbits;
        for (int q = t; q < NN / 4; q += 256) sbits4[q] = drow4[q];
    }
    if (t == 0) { s_sel[0] = 127u; s_sel[1] = 0u; s_sel[2] = 0u; }
    __syncthreads();

    // Phase 2: 4-pass radix select -> exact bits of 128th smallest (vstar)
    for (int pass = 0; pass < 4; ++pass) {
        const int shift = 24 - 8 * pass;
        const unsigned int highmask = pass ? (0xFFFFFFFFu << (shift + 8)) : 0u;
        hist[t] = 0u;
        __syncthreads();
        const unsigned int prefix = s_sel[1];
        for (int i = t; i < NN; i += 256) {
            unsigned int v = sbits[i];
            if ((v & highmask) == prefix)
                atomicAdd(&hist[(v >> shift) & 255u], 1u);
        }
        __syncthreads();
        if (t == 0) {
            unsigned int r = s_sel[0];
            unsigned int cum = 0;
            for (int b = 0; b < 256; ++b) {
                unsigned int c = hist[b];
                if (r < cum + c) {
                    s_sel[0] = r - cum;
                    s_sel[1] = prefix | ((unsigned int)b << shift);
                    break;
                }
                cum += c;
            }
        }
        __syncthreads();
    }
    const unsigned int vstar = s_sel[1];

    // Phase 3: collect candidates (bits <= vstar) as packed (bits,idx) keys
    for (int i = t; i < NN; i += 256) {
        unsigned int v = sbits[i];
        if (v <= vstar) {
            unsigned int pos = atomicAdd(&s_sel[2], 1u);
            if (pos < 512u) cand[pos] = ((unsigned long long)v << 32) | (unsigned int)i;
        }
    }
    __syncthreads();
    const unsigned int ncand = s_sel[2] < 512u ? s_sel[2] : 512u;
    for (int i = t; i < 512; i += 256)
        if ((unsigned int)i >= ncand) cand[i] = ~0ULL;

    // sbits no longer needed: stage theta row for LDS gather
    float* stheta = (float*)sbits;
    {
        const float4* trow4 = (const float4*)(theta + (size_t)row * NN);
        float4* st4 = (float4*)stheta;
        for (int q = t; q < NN / 4; q += 256) st4[q] = trow4[q];
    }
    __syncthreads();

    // Phase 4: bitonic sort 512 packed keys ascending (== top_k order incl. tie-break)
    for (int k = 2; k <= 512; k <<= 1) {
        for (int jj = k >> 1; jj > 0; jj >>= 1) {
            for (int i = t; i < 512; i += 256) {
                int ixj = i ^ jj;
                if (ixj > i) {
                    unsigned long long a = cand[i], b = cand[ixj];
                    bool up = ((i & k) == 0);
                    if ((a > b) == up) { cand[i] = b; cand[ixj] = a; }
                }
            }
            __syncthreads();
        }
    }

    // Phase 5: emit sorted idx, normalized dist, gathered theta, features
    const float dmax = __uint_as_float((unsigned int)(cand[127] >> 32));
    float* xrow = xin + (size_t)row * KPAD;
    if (t < 128) {
        unsigned long long key = cand[t];
        unsigned int ij = (unsigned int)key;
        float dv = __uint_as_float((unsigned int)(key >> 32));
        gidx[(size_t)row * LL + t] = (int)ij;
        xrow[t] = dv / dmax;
        xrow[128 + t] = stheta[ij];
    } else if (t == 128) {
        xrow[256] = f0[row];
        xrow[257] = f1[row];
        #pragma unroll
        for (int z = DIN; z < KPAD; ++z) xrow[z] = 0.0f;
    }
}

// ---------------- Kernel C: val = xin @ Wc + bc - dn  (fp32 SGEMM, 128x128 tiles) ----------------
__global__ __launch_bounds__(256) void kC(const float* __restrict__ xin,
                                          const float* __restrict__ Wc,
                                          const float* __restrict__ bc,
                                          float* __restrict__ val) {
    __shared__ __align__(16) float As[8][132];
    __shared__ __align__(16) float Bs[8][128];
    const int t = threadIdx.x;
    const int tr = t >> 4, tc = t & 15;
    const int row0 = blockIdx.x * 128;
    float acc[8][8];
    #pragma unroll
    for (int i = 0; i < 8; ++i)
        #pragma unroll
        for (int j = 0; j < 8; ++j) acc[i][j] = 0.f;

    for (int kc = 0; kc < KPAD; kc += 8) {
        #pragma unroll
        for (int q = 0; q < 4; ++q) {
            int linear = q * 256 + t;
            int m = linear >> 3, k = linear & 7;
            As[k][m] = xin[(size_t)(row0 + m) * KPAD + kc + k];
        }
        #pragma unroll
        for (int q = 0; q < 4; ++q) {
            int linear = q * 256 + t;
            int k = linear >> 7, c = linear & 127;
            Bs[k][c] = Wc[(kc + k) * LL + c];
        }
        __syncthreads();
        #pragma unroll
        for (int k = 0; k < 8; ++k) {
            float a[8], b[8];
            *(float4*)&a[0] = *(const float4*)&As[k][tr * 8];
            *(float4*)&a[4] = *(const float4*)&As[k][tr * 8 + 4];
            *(float4*)&b[0] = *(const float4*)&Bs[k][tc * 8];
            *(float4*)&b[4] = *(const float4*)&Bs[k][tc * 8 + 4];
            #pragma unroll
            for (int i = 0; i < 8; ++i)
                #pragma unroll
                for (int j = 0; j < 8; ++j)
                    acc[i][j] += a[i] * b[j];
        }
        __syncthreads();
    }
    #pragma unroll
    for (int i = 0; i < 8; ++i) {
        int r = row0 + tr * 8 + i;
        #pragma unroll
        for (int j = 0; j < 8; ++j) {
            int c = tc * 8 + j;
            val[(size_t)r * LL + c] = acc[i][j] + bc[c] - xin[(size_t)r * KPAD + c];
        }
    }
}

// ---------------- Kernel D: fill PENALTY row + scatter, stream out ----------------
__global__ __launch_bounds__(256) void kD(const int* __restrict__ gidx,
                                          const float* __restrict__ val,
                                          float* __restrict__ out) {
    __shared__ __align__(16) float rowbuf[NN];
    const int t = threadIdx.x;
    const int row = blockIdx.x;
    for (int i = t; i < NN; i += 256) rowbuf[i] = PENALTY_V;
    __syncthreads();
    if (t < 128) rowbuf[gidx[(size_t)row * LL + t]] = val[(size_t)row * LL + t];
    __syncthreads();
    float4* out4 = (float4*)(out + (size_t)row * NN);
    const float4* rb4 = (const float4*)rowbuf;
    for (int q = t; q < NN / 4; q += 256) out4[q] = rb4[q];
}

extern "C" void kernel_launch(void* const* d_in, const int* in_sizes, int n_in,
                              void* d_out, int out_size, void* d_ws, size_t ws_size,
                              hipStream_t stream) {
    const float* theta = (const float*)d_in[0];
    const float* dist  = (const float*)d_in[1];
    const float* f0    = (const float*)d_in[2];
    const float* f1    = (const float*)d_in[3];
    const float* W1    = (const float*)d_in[4];
    const float* b1    = (const float*)d_in[5];
    const float* W2    = (const float*)d_in[6];
    const float* b2    = (const float*)d_in[7];
    float* out = (float*)d_out;

    char* ws = (char*)d_ws;
    float* Wc   = (float*)ws;                                   // KPAD*128*4 = 135168
    float* bc   = (float*)(ws + 135168);                        // 512
    float* xin  = (float*)(ws + 135680);                        // NROWS*KPAD*4 = 16896000
    int*   gidx = (int*)  (ws + 135680 + 16896000);             // NROWS*128*4 = 8192000
    float* val  = (float*)(ws + 135680 + 16896000 + 8192000);   // NROWS*128*4 = 8192000

    kA<<<(KPAD / 8), 256, 0, stream>>>(W1, b1, W2, b2, Wc, bc);
    kB<<<NROWS, 256, 0, stream>>>(dist, theta, f0, f1, xin, gidx);
    kC<<<NROWS / 128, 256, 0, stream>>>(xin, Wc, bc, val);
    kD<<<NROWS, 256, 0, stream>>>(gidx, val, out);
}

// Round 2
// 291.427 us; speedup vs baseline: 2.5513x; 2.5513x over previous
//
#include <hip/hip_runtime.h>
#include <hip/hip_bf16.h>

#define BN 8
#define NN 2000
#define LL 128
#define EE 2048
#define DIN 258
#define KPAD 264
#define NROWS (BN*NN)
#define PENALTY_V 10.0f
#define NBINS 1024
#define CANDCAP 512

// ---------------- Kernel A: Wc = W1@W2 (KPAD x 128), bc = b1@W2 + b2 ----------------
__global__ __launch_bounds__(256) void kA(const float* __restrict__ W1,
                                          const float* __restrict__ b1,
                                          const float* __restrict__ W2,
                                          const float* __restrict__ b2,
                                          float* __restrict__ Wc,
                                          float* __restrict__ bc) {
    __shared__ float As2[8][64];
    const int t = threadIdx.x;
    const int j = t & 127;
    const int half = t >> 7;          // 0 or 1
    const int k0 = blockIdx.x * 8;    // 33 blocks cover rows 0..263
    float acc[4] = {0.f, 0.f, 0.f, 0.f};
    for (int ec = 0; ec < EE; ec += 64) {
        #pragma unroll
        for (int q = 0; q < 2; ++q) {
            int linear = q * 256 + t;
            int r8 = linear >> 6;
            int e  = linear & 63;
            int k  = k0 + r8;
            float v;
            if (k < DIN)       v = W1[k * EE + ec + e];
            else if (k == DIN) v = b1[ec + e];
            else               v = 0.0f;
            As2[r8][e] = v;
        }
        __syncthreads();
        #pragma unroll 8
        for (int e = 0; e < 64; ++e) {
            float w = W2[(ec + e) * LL + j];
            #pragma unroll
            for (int rr = 0; rr < 4; ++rr)
                acc[rr] += As2[half * 4 + rr][e] * w;
        }
        __syncthreads();
    }
    #pragma unroll
    for (int rr = 0; rr < 4; ++rr) {
        int k = k0 + half * 4 + rr;
        if (k == DIN) {
            bc[j] = acc[rr] + b2[j];
            Wc[k * LL + j] = 0.0f;
        } else if (k < KPAD) {
            Wc[k * LL + j] = (k < DIN) ? acc[rr] : 0.0f;
        }
    }
}

// ---------------- Kernel B: per-row top-128 via linear-bucket select + rank sort ----------------
__global__ __launch_bounds__(256) void kB(const float* __restrict__ dist,
                                          const float* __restrict__ theta,
                                          const float* __restrict__ f0,
                                          const float* __restrict__ f1,
                                          float* __restrict__ xin,
                                          int*   __restrict__ gidx) {
    __shared__ unsigned int sbits[NN];                 // 8000 B (reused for theta row later)
    __shared__ unsigned int hist[NBINS];               // 4096 B: counts -> exclusive prefix
    __shared__ unsigned long long cand[CANDCAP];       // 4096 B
    __shared__ unsigned int wred[4];                   // wave partials (max / scan)
    __shared__ float s_out_d[LL];
    __shared__ int   s_out_i[LL];
    __shared__ unsigned int s_cnt;

    const int t = threadIdx.x;
    const int lane = t & 63;
    const int w = t >> 6;                              // 4 waves
    const int row = blockIdx.x;

    // Phase 1: init hist, load dist row bits, track local max (uint-monotone for positive floats)
    #pragma unroll
    for (int q = 0; q < NBINS / 256; ++q) hist[t + q * 256] = 0u;
    if (t == 0) s_cnt = 0u;
    unsigned int lmax = 0u;
    {
        const uint4* drow4 = (const uint4*)(dist + (size_t)row * NN);
        uint4* sbits4 = (uint4*)sbits;
        for (int q = t; q < NN / 4; q += 256) {
            uint4 v = drow4[q];
            sbits4[q] = v;
            lmax = max(max(max(lmax, v.x), max(v.y, v.z)), v.w);
        }
    }
    // wave max-reduce, then cross-wave
    #pragma unroll
    for (int d = 32; d > 0; d >>= 1) lmax = max(lmax, (unsigned int)__shfl_down((int)lmax, d));
    if (lane == 0) wred[w] = lmax;
    __syncthreads();
    const unsigned int vmax_bits = max(max(wred[0], wred[1]), max(wred[2], wred[3]));
    const float scale = (float)(NBINS - 1) / __uint_as_float(vmax_bits);
    __syncthreads();   // wred reused by scan below

    // Phase 2: single-pass histogram on linear buckets (monotone in v, ~2 elems/bin)
    for (int i = t; i < NN; i += 256) {
        float v = __uint_as_float(sbits[i]);
        int b = (int)(v * scale);
        b = b < 0 ? 0 : (b > NBINS - 1 ? NBINS - 1 : b);
        atomicAdd(&hist[b], 1u);
    }
    __syncthreads();

    // Phase 3: block-parallel exclusive prefix scan of hist (4 bins per thread)
    {
        const int base = t * (NBINS / 256);
        unsigned int loc[NBINS / 256];
        unsigned int run = 0;
        #pragma unroll
        for (int q = 0; q < NBINS / 256; ++q) { loc[q] = run; run += hist[base + q]; }
        unsigned int inc = run;
        #pragma unroll
        for (int d = 1; d < 64; d <<= 1) {
            unsigned int o = (unsigned int)__shfl_up((int)inc, d);
            if (lane >= d) inc += o;
        }
        if (lane == 63) wred[w] = inc;
        __syncthreads();
        unsigned int woff = 0;
        for (int k = 0; k < 4; ++k) if (k < w) woff += wred[k];
        const unsigned int texcl = woff + inc - run;
        #pragma unroll
        for (int q = 0; q < NBINS / 256; ++q) hist[base + q] = texcl + loc[q];
    }
    __syncthreads();

    // Phase 4: collect candidates (bucket's exclusive prefix < 128 => may hold rank<=127)
    for (int i = t; i < NN; i += 256) {
        unsigned int vb = sbits[i];
        float v = __uint_as_float(vb);
        int b = (int)(v * scale);
        b = b < 0 ? 0 : (b > NBINS - 1 ? NBINS - 1 : b);
        if (hist[b] < (unsigned int)LL) {
            unsigned int pos = atomicAdd(&s_cnt, 1u);
            if (pos < CANDCAP) cand[pos] = ((unsigned long long)vb << 32) | (unsigned int)i;
        }
    }
    __syncthreads();
    const unsigned int ncand = s_cnt < CANDCAP ? s_cnt : CANDCAP;

    // Phase 5a: stage theta row into LDS (sbits free now)
    float* stheta = (float*)sbits;
    {
        const float4* trow4 = (const float4*)(theta + (size_t)row * NN);
        float4* st4 = (float4*)stheta;
        for (int q = t; q < NN / 4; q += 256) st4[q] = trow4[q];
    }
    // Phase 5b: exact rank of each candidate among candidates by (bits,idx); keys are unique
    for (unsigned int i = t; i < ncand; i += 256) {
        const unsigned long long key = cand[i];
        unsigned int r = 0;
        for (unsigned int j = 0; j < ncand; ++j) r += (cand[j] < key);
        if (r < (unsigned int)LL) {
            s_out_d[r] = __uint_as_float((unsigned int)(key >> 32));
            s_out_i[r] = (int)(unsigned int)key;
        }
    }
    __syncthreads();

    // Phase 6: emit sorted idx, normalized dist, gathered theta, features
    const float dmax = s_out_d[LL - 1];
    float* xrow = xin + (size_t)row * KPAD;
    if (t < LL) {
        float dv = s_out_d[t];
        int ij = s_out_i[t];
        gidx[(size_t)row * LL + t] = ij;
        xrow[t] = dv / dmax;
        xrow[LL + t] = stheta[ij];
    } else if (t == LL) {
        xrow[256] = f0[row];
        xrow[257] = f1[row];
        #pragma unroll
        for (int z = DIN; z < KPAD; ++z) xrow[z] = 0.0f;
    }
}

// ---------------- Kernel C: val = xin @ Wc + bc - dn  (fp32 SGEMM, 128x128 tiles) ----------------
__global__ __launch_bounds__(256) void kC(const float* __restrict__ xin,
                                          const float* __restrict__ Wc,
                                          const float* __restrict__ bc,
                                          float* __restrict__ val) {
    __shared__ __align__(16) float As[8][132];
    __shared__ __align__(16) float Bs[8][128];
    const int t = threadIdx.x;
    const int tr = t >> 4, tc = t & 15;
    const int row0 = blockIdx.x * 128;
    float acc[8][8];
    #pragma unroll
    for (int i = 0; i < 8; ++i)
        #pragma unroll
        for (int j = 0; j < 8; ++j) acc[i][j] = 0.f;

    for (int kc = 0; kc < KPAD; kc += 8) {
        #pragma unroll
        for (int q = 0; q < 4; ++q) {
            int linear = q * 256 + t;
            int m = linear >> 3, k = linear & 7;
            As[k][m] = xin[(size_t)(row0 + m) * KPAD + kc + k];
        }
        #pragma unroll
        for (int q = 0; q < 4; ++q) {
            int linear = q * 256 + t;
            int k = linear >> 7, c = linear & 127;
            Bs[k][c] = Wc[(kc + k) * LL + c];
        }
        __syncthreads();
        #pragma unroll
        for (int k = 0; k < 8; ++k) {
            float a[8], b[8];
            *(float4*)&a[0] = *(const float4*)&As[k][tr * 8];
            *(float4*)&a[4] = *(const float4*)&As[k][tr * 8 + 4];
            *(float4*)&b[0] = *(const float4*)&Bs[k][tc * 8];
            *(float4*)&b[4] = *(const float4*)&Bs[k][tc * 8 + 4];
            #pragma unroll
            for (int i = 0; i < 8; ++i)
                #pragma unroll
                for (int j = 0; j < 8; ++j)
                    acc[i][j] += a[i] * b[j];
        }
        __syncthreads();
    }
    #pragma unroll
    for (int i = 0; i < 8; ++i) {
        int r = row0 + tr * 8 + i;
        #pragma unroll
        for (int j = 0; j < 8; ++j) {
            int c = tc * 8 + j;
            val[(size_t)r * LL + c] = acc[i][j] + bc[c] - xin[(size_t)r * KPAD + c];
        }
    }
}

// ---------------- Kernel D: fill PENALTY row + scatter, stream out ----------------
__global__ __launch_bounds__(256) void kD(const int* __restrict__ gidx,
                                          const float* __restrict__ val,
                                          float* __restrict__ out) {
    __shared__ __align__(16) float rowbuf[NN];
    const int t = threadIdx.x;
    const int row = blockIdx.x;
    for (int i = t; i < NN; i += 256) rowbuf[i] = PENALTY_V;
    __syncthreads();
    if (t < 128) rowbuf[gidx[(size_t)row * LL + t]] = val[(size_t)row * LL + t];
    __syncthreads();
    float4* out4 = (float4*)(out + (size_t)row * NN);
    const float4* rb4 = (const float4*)rowbuf;
    for (int q = t; q < NN / 4; q += 256) out4[q] = rb4[q];
}

extern "C" void kernel_launch(void* const* d_in, const int* in_sizes, int n_in,
                              void* d_out, int out_size, void* d_ws, size_t ws_size,
                              hipStream_t stream) {
    const float* theta = (const float*)d_in[0];
    const float* dist  = (const float*)d_in[1];
    const float* f0    = (const float*)d_in[2];
    const float* f1    = (const float*)d_in[3];
    const float* W1    = (const float*)d_in[4];
    const float* b1    = (const float*)d_in[5];
    const float* W2    = (const float*)d_in[6];
    const float* b2    = (const float*)d_in[7];
    float* out = (float*)d_out;

    char* ws = (char*)d_ws;
    float* Wc   = (float*)ws;                                   // KPAD*128*4 = 135168
    float* bc   = (float*)(ws + 135168);                        // 512
    float* xin  = (float*)(ws + 135680);                        // NROWS*KPAD*4 = 16896000
    int*   gidx = (int*)  (ws + 135680 + 16896000);             // NROWS*128*4 = 8192000
    float* val  = (float*)(ws + 135680 + 16896000 + 8192000);   // NROWS*128*4 = 8192000

    kA<<<(KPAD / 8), 256, 0, stream>>>(W1, b1, W2, b2, Wc, bc);
    kB<<<NROWS, 256, 0, stream>>>(dist, theta, f0, f1, xin, gidx);
    kC<<<NROWS / 128, 256, 0, stream>>>(xin, Wc, bc, val);
    kD<<<NROWS, 256, 0, stream>>>(gidx, val, out);
}

// Round 3
// 164.723 us; speedup vs baseline: 4.5138x; 1.7692x over previous
//
#include <hip/hip_runtime.h>
#include <hip/hip_bf16.h>

#define BN 8
#define NN 2000
#define LL 128
#define EE 2048
#define DIN 258
#define KPAD 264
#define NROWS (BN*NN)
#define PENALTY_V 10.0f
#define NBINS 1024
#define CANDCAP 512
#define SPLITK 16
#define ECHUNK (EE/SPLITK)   // 128

// ---------------- Kernel A1: partial Wc = W1@W2 over one K-slice ----------------
__global__ __launch_bounds__(256) void kA1(const float* __restrict__ W1,
                                           const float* __restrict__ b1,
                                           const float* __restrict__ W2,
                                           float* __restrict__ part) {
    __shared__ float As2[8][64];
    const int t = threadIdx.x;
    const int j = t & 127;
    const int half = t >> 7;              // 0 or 1
    const int rg = blockIdx.x >> 4;       // row group 0..32
    const int ks = blockIdx.x & 15;       // K slice 0..15
    const int k0 = rg * 8;
    const int ebase = ks * ECHUNK;
    float acc[4] = {0.f, 0.f, 0.f, 0.f};
    for (int ec = ebase; ec < ebase + ECHUNK; ec += 64) {
        #pragma unroll
        for (int q = 0; q < 2; ++q) {
            int linear = q * 256 + t;
            int r8 = linear >> 6;
            int e  = linear & 63;
            int k  = k0 + r8;
            float v;
            if (k < DIN)       v = W1[k * EE + ec + e];
            else if (k == DIN) v = b1[ec + e];
            else               v = 0.0f;
            As2[r8][e] = v;
        }
        __syncthreads();
        #pragma unroll 8
        for (int e = 0; e < 64; ++e) {
            float w = W2[(ec + e) * LL + j];
            #pragma unroll
            for (int rr = 0; rr < 4; ++rr)
                acc[rr] += As2[half * 4 + rr][e] * w;
        }
        __syncthreads();
    }
    #pragma unroll
    for (int rr = 0; rr < 4; ++rr) {
        int k = k0 + half * 4 + rr;       // < KPAD always (max 263)
        part[(size_t)ks * (KPAD * LL) + k * LL + j] = acc[rr];
    }
}

// ---------------- Kernel A2: reduce partials -> Wc, bc ----------------
__global__ __launch_bounds__(256) void kA2(const float* __restrict__ part,
                                           const float* __restrict__ b2,
                                           float* __restrict__ Wc,
                                           float* __restrict__ bc) {
    const int i = blockIdx.x * 256 + threadIdx.x;   // 0..KPAD*LL-1
    float s = 0.f;
    #pragma unroll
    for (int q = 0; q < SPLITK; ++q) s += part[(size_t)q * (KPAD * LL) + i];
    const int k = i >> 7;
    const int j = i & 127;
    if (k == DIN)      { bc[j] = s + b2[j]; Wc[i] = 0.f; }
    else if (k > DIN)  { Wc[i] = 0.f; }
    else               { Wc[i] = s; }
}

// ---------------- Kernel B: per-row top-128 via linear-bucket select + rank sort ----------------
__global__ __launch_bounds__(256) void kB(const float* __restrict__ dist,
                                          const float* __restrict__ theta,
                                          const float* __restrict__ f0,
                                          const float* __restrict__ f1,
                                          float* __restrict__ xin,
                                          int*   __restrict__ gidx) {
    __shared__ unsigned int sbits[NN];                 // 8000 B (reused for theta row later)
    __shared__ unsigned int hist[NBINS];               // 4096 B: counts -> exclusive prefix
    __shared__ unsigned long long cand[CANDCAP];       // 4096 B
    __shared__ unsigned int wred[4];                   // wave partials (max / scan)
    __shared__ float s_out_d[LL];
    __shared__ int   s_out_i[LL];
    __shared__ unsigned int s_cnt;

    const int t = threadIdx.x;
    const int lane = t & 63;
    const int w = t >> 6;                              // 4 waves
    const int row = blockIdx.x;

    // Phase 1: init hist, load dist row bits, track local max (uint-monotone for positive floats)
    #pragma unroll
    for (int q = 0; q < NBINS / 256; ++q) hist[t + q * 256] = 0u;
    if (t == 0) s_cnt = 0u;
    unsigned int lmax = 0u;
    {
        const uint4* drow4 = (const uint4*)(dist + (size_t)row * NN);
        uint4* sbits4 = (uint4*)sbits;
        for (int q = t; q < NN / 4; q += 256) {
            uint4 v = drow4[q];
            sbits4[q] = v;
            lmax = max(max(max(lmax, v.x), max(v.y, v.z)), v.w);
        }
    }
    #pragma unroll
    for (int d = 32; d > 0; d >>= 1) lmax = max(lmax, (unsigned int)__shfl_down((int)lmax, d));
    if (lane == 0) wred[w] = lmax;
    __syncthreads();
    const unsigned int vmax_bits = max(max(wred[0], wred[1]), max(wred[2], wred[3]));
    const float scale = (float)(NBINS - 1) / __uint_as_float(vmax_bits);
    __syncthreads();   // wred reused by scan below

    // Phase 2: single-pass histogram on linear buckets (monotone in v, ~2 elems/bin)
    for (int i = t; i < NN; i += 256) {
        float v = __uint_as_float(sbits[i]);
        int b = (int)(v * scale);
        b = b < 0 ? 0 : (b > NBINS - 1 ? NBINS - 1 : b);
        atomicAdd(&hist[b], 1u);
    }
    __syncthreads();

    // Phase 3: block-parallel exclusive prefix scan of hist (4 bins per thread)
    {
        const int base = t * (NBINS / 256);
        unsigned int loc[NBINS / 256];
        unsigned int run = 0;
        #pragma unroll
        for (int q = 0; q < NBINS / 256; ++q) { loc[q] = run; run += hist[base + q]; }
        unsigned int inc = run;
        #pragma unroll
        for (int d = 1; d < 64; d <<= 1) {
            unsigned int o = (unsigned int)__shfl_up((int)inc, d);
            if (lane >= d) inc += o;
        }
        if (lane == 63) wred[w] = inc;
        __syncthreads();
        unsigned int woff = 0;
        for (int k = 0; k < 4; ++k) if (k < w) woff += wred[k];
        const unsigned int texcl = woff + inc - run;
        #pragma unroll
        for (int q = 0; q < NBINS / 256; ++q) hist[base + q] = texcl + loc[q];
    }
    __syncthreads();

    // Phase 4: collect candidates (bucket's exclusive prefix < 128 => may hold rank<=127)
    for (int i = t; i < NN; i += 256) {
        unsigned int vb = sbits[i];
        float v = __uint_as_float(vb);
        int b = (int)(v * scale);
        b = b < 0 ? 0 : (b > NBINS - 1 ? NBINS - 1 : b);
        if (hist[b] < (unsigned int)LL) {
            unsigned int pos = atomicAdd(&s_cnt, 1u);
            if (pos < CANDCAP) cand[pos] = ((unsigned long long)vb << 32) | (unsigned int)i;
        }
    }
    __syncthreads();
    const unsigned int ncand = s_cnt < CANDCAP ? s_cnt : CANDCAP;

    // Phase 5a: stage theta row into LDS (sbits free now)
    float* stheta = (float*)sbits;
    {
        const float4* trow4 = (const float4*)(theta + (size_t)row * NN);
        float4* st4 = (float4*)stheta;
        for (int q = t; q < NN / 4; q += 256) st4[q] = trow4[q];
    }
    // Phase 5b: exact rank of each candidate among candidates by (bits,idx); keys are unique
    for (unsigned int i = t; i < ncand; i += 256) {
        const unsigned long long key = cand[i];
        unsigned int r = 0;
        for (unsigned int j = 0; j < ncand; ++j) r += (cand[j] < key);
        if (r < (unsigned int)LL) {
            s_out_d[r] = __uint_as_float((unsigned int)(key >> 32));
            s_out_i[r] = (int)(unsigned int)key;
        }
    }
    __syncthreads();

    // Phase 6: emit sorted idx, normalized dist, gathered theta, features
    const float dmax = s_out_d[LL - 1];
    float* xrow = xin + (size_t)row * KPAD;
    if (t < LL) {
        float dv = s_out_d[t];
        int ij = s_out_i[t];
        gidx[(size_t)row * LL + t] = ij;
        xrow[t] = dv / dmax;
        xrow[LL + t] = stheta[ij];
    } else if (t == LL) {
        xrow[256] = f0[row];
        xrow[257] = f1[row];
        #pragma unroll
        for (int z = DIN; z < KPAD; ++z) xrow[z] = 0.0f;
    }
}

// ---------------- Kernel C: val = xin @ Wc + bc - dn  (fp32 SGEMM, 128x128 tiles) ----------------
__global__ __launch_bounds__(256) void kC(const float* __restrict__ xin,
                                          const float* __restrict__ Wc,
                                          const float* __restrict__ bc,
                                          float* __restrict__ val) {
    __shared__ __align__(16) float As[8][132];
    __shared__ __align__(16) float Bs[8][128];
    const int t = threadIdx.x;
    const int tr = t >> 4, tc = t & 15;
    const int row0 = blockIdx.x * 128;
    float acc[8][8];
    #pragma unroll
    for (int i = 0; i < 8; ++i)
        #pragma unroll
        for (int j = 0; j < 8; ++j) acc[i][j] = 0.f;

    for (int kc = 0; kc < KPAD; kc += 8) {
        #pragma unroll
        for (int q = 0; q < 4; ++q) {
            int linear = q * 256 + t;
            int m = linear >> 3, k = linear & 7;
            As[k][m] = xin[(size_t)(row0 + m) * KPAD + kc + k];
        }
        #pragma unroll
        for (int q = 0; q < 4; ++q) {
            int linear = q * 256 + t;
            int k = linear >> 7, c = linear & 127;
            Bs[k][c] = Wc[(kc + k) * LL + c];
        }
        __syncthreads();
        #pragma unroll
        for (int k = 0; k < 8; ++k) {
            float a[8], b[8];
            *(float4*)&a[0] = *(const float4*)&As[k][tr * 8];
            *(float4*)&a[4] = *(const float4*)&As[k][tr * 8 + 4];
            *(float4*)&b[0] = *(const float4*)&Bs[k][tc * 8];
            *(float4*)&b[4] = *(const float4*)&Bs[k][tc * 8 + 4];
            #pragma unroll
            for (int i = 0; i < 8; ++i)
                #pragma unroll
                for (int j = 0; j < 8; ++j)
                    acc[i][j] += a[i] * b[j];
        }
        __syncthreads();
    }
    #pragma unroll
    for (int i = 0; i < 8; ++i) {
        int r = row0 + tr * 8 + i;
        #pragma unroll
        for (int j = 0; j < 8; ++j) {
            int c = tc * 8 + j;
            val[(size_t)r * LL + c] = acc[i][j] + bc[c] - xin[(size_t)r * KPAD + c];
        }
    }
}

// ---------------- Kernel D: fill PENALTY row + scatter, stream out ----------------
__global__ __launch_bounds__(256) void kD(const int* __restrict__ gidx,
                                          const float* __restrict__ val,
                                          float* __restrict__ out) {
    __shared__ __align__(16) float rowbuf[NN];
    const int t = threadIdx.x;
    const int row = blockIdx.x;
    for (int i = t; i < NN; i += 256) rowbuf[i] = PENALTY_V;
    __syncthreads();
    if (t < 128) rowbuf[gidx[(size_t)row * LL + t]] = val[(size_t)row * LL + t];
    __syncthreads();
    float4* out4 = (float4*)(out + (size_t)row * NN);
    const float4* rb4 = (const float4*)rowbuf;
    for (int q = t; q < NN / 4; q += 256) out4[q] = rb4[q];
}

extern "C" void kernel_launch(void* const* d_in, const int* in_sizes, int n_in,
                              void* d_out, int out_size, void* d_ws, size_t ws_size,
                              hipStream_t stream) {
    const float* theta = (const float*)d_in[0];
    const float* dist  = (const float*)d_in[1];
    const float* f0    = (const float*)d_in[2];
    const float* f1    = (const float*)d_in[3];
    const float* W1    = (const float*)d_in[4];
    const float* b1    = (const float*)d_in[5];
    const float* W2    = (const float*)d_in[6];
    const float* b2    = (const float*)d_in[7];
    float* out = (float*)d_out;

    char* ws = (char*)d_ws;
    float* Wc   = (float*)ws;                                   // KPAD*128*4 = 135168
    float* bc   = (float*)(ws + 135168);                        // 512
    float* xin  = (float*)(ws + 135680);                        // NROWS*KPAD*4 = 16896000
    int*   gidx = (int*)  (ws + 135680 + 16896000);             // NROWS*128*4 = 8192000
    float* val  = (float*)(ws + 135680 + 16896000 + 8192000);   // NROWS*128*4 = 8192000
    // part aliases val: kA1 writes it, kA2 consumes it, kC later overwrites val.
    float* part = val;                                          // SPLITK*KPAD*128*4 = 2162688 <= 8192000

    kA1<<<33 * SPLITK, 256, 0, stream>>>(W1, b1, W2, part);
    kA2<<<(KPAD * LL) / 256, 256, 0, stream>>>(part, b2, Wc, bc);
    kB<<<NROWS, 256, 0, stream>>>(dist, theta, f0, f1, xin, gidx);
    kC<<<NROWS / 128, 256, 0, stream>>>(xin, Wc, bc, val);
    kD<<<NROWS, 256, 0, stream>>>(gidx, val, out);
}

// Round 4
// 146.158 us; speedup vs baseline: 5.0872x; 1.1270x over previous
//
#include <hip/hip_runtime.h>
#include <hip/hip_bf16.h>

#define BN 8
#define NN 2000
#define LL 128
#define EE 2048
#define DIN 258
#define KPAD 264
#define NROWS (BN*NN)
#define PENALTY_V 10.0f
#define NBINS 1024
#define CANDCAP 256
#define SPLITK 16
#define ECHUNK (EE/SPLITK)   // 128

// ---------------- Kernel A1: partial Wc = W1@W2 over one K-slice ----------------
__global__ __launch_bounds__(256) void kA1(const float* __restrict__ W1,
                                           const float* __restrict__ b1,
                                           const float* __restrict__ W2,
                                           float* __restrict__ part) {
    __shared__ float As2[8][64];
    const int t = threadIdx.x;
    const int j = t & 127;
    const int half = t >> 7;              // 0 or 1
    const int rg = blockIdx.x >> 4;       // row group 0..32
    const int ks = blockIdx.x & 15;       // K slice 0..15
    const int k0 = rg * 8;
    const int ebase = ks * ECHUNK;
    float acc[4] = {0.f, 0.f, 0.f, 0.f};
    for (int ec = ebase; ec < ebase + ECHUNK; ec += 64) {
        #pragma unroll
        for (int q = 0; q < 2; ++q) {
            int linear = q * 256 + t;
            int r8 = linear >> 6;
            int e  = linear & 63;
            int k  = k0 + r8;
            float v;
            if (k < DIN)       v = W1[k * EE + ec + e];
            else if (k == DIN) v = b1[ec + e];
            else               v = 0.0f;
            As2[r8][e] = v;
        }
        __syncthreads();
        #pragma unroll 8
        for (int e = 0; e < 64; ++e) {
            float w = W2[(ec + e) * LL + j];
            #pragma unroll
            for (int rr = 0; rr < 4; ++rr)
                acc[rr] += As2[half * 4 + rr][e] * w;
        }
        __syncthreads();
    }
    #pragma unroll
    for (int rr = 0; rr < 4; ++rr) {
        int k = k0 + half * 4 + rr;       // < KPAD always (max 263)
        part[(size_t)ks * (KPAD * LL) + k * LL + j] = acc[rr];
    }
}

// ---------------- Kernel A2: reduce partials -> Wc, bc ----------------
__global__ __launch_bounds__(256) void kA2(const float* __restrict__ part,
                                           const float* __restrict__ b2,
                                           float* __restrict__ Wc,
                                           float* __restrict__ bc) {
    const int i = blockIdx.x * 256 + threadIdx.x;   // 0..KPAD*LL-1
    float s = 0.f;
    #pragma unroll
    for (int q = 0; q < SPLITK; ++q) s += part[(size_t)q * (KPAD * LL) + i];
    const int k = i >> 7;
    const int j = i & 127;
    if (k == DIN)      { bc[j] = s + b2[j]; Wc[i] = 0.f; }
    else if (k > DIN)  { Wc[i] = 0.f; }
    else               { Wc[i] = s; }
}

// ---- Kernel B: per-row top-128, register-resident + positional bucket placement ----
__global__ __launch_bounds__(256) void kB(const float* __restrict__ dist,
                                          const float* __restrict__ theta,
                                          const float* __restrict__ f0,
                                          const float* __restrict__ f1,
                                          float* __restrict__ xin,
                                          int*   __restrict__ gidx) {
    __shared__ unsigned int hist[NBINS];     // counts -> cursor (end after placement)
    __shared__ unsigned int starts[NBINS];   // pristine exclusive prefix
    __shared__ unsigned long long cand[CANDCAP];
    __shared__ unsigned int wred[4];

    const int t = threadIdx.x;
    const int lane = t & 63;
    const int w = t >> 6;
    const int row = blockIdx.x;

    // Step 1: init hist + cand
    #pragma unroll
    for (int q = 0; q < NBINS / 256; ++q) hist[t + q * 256] = 0u;
    cand[t & (CANDCAP - 1)] = ~0ULL;

    // Step 2: load 8 consecutive elements into registers (thread t owns 8t..8t+7, t<250)
    unsigned int v[8];
    const bool has = (t < 250);
    unsigned int lmax = 0u;
    if (has) {
        const uint4* drow4 = (const uint4*)(dist + (size_t)row * NN);
        uint4 a = drow4[2 * t];
        uint4 b = drow4[2 * t + 1];
        v[0] = a.x; v[1] = a.y; v[2] = a.z; v[3] = a.w;
        v[4] = b.x; v[5] = b.y; v[6] = b.z; v[7] = b.w;
        #pragma unroll
        for (int k = 0; k < 8; ++k) lmax = max(lmax, v[k]);
    }
    #pragma unroll
    for (int d = 32; d > 0; d >>= 1) lmax = max(lmax, (unsigned int)__shfl_down((int)lmax, d));
    if (lane == 0) wred[w] = lmax;
    __syncthreads();   // hist/cand init + wred done

    // Step 3: scale from row max (uint-bit max == float max for positive floats)
    const unsigned int vmax_bits = max(max(wred[0], wred[1]), max(wred[2], wred[3]));
    const float scale = (float)(NBINS - 1) / __uint_as_float(vmax_bits);

    // Step 4: histogram (buckets kept in registers)
    int bk[8];
    if (has) {
        #pragma unroll
        for (int k = 0; k < 8; ++k) {
            float f = __uint_as_float(v[k]);
            int b = (int)(f * scale);
            bk[k] = b < 0 ? 0 : (b > NBINS - 1 ? NBINS - 1 : b);
            atomicAdd(&hist[bk[k]], 1u);
        }
    }
    __syncthreads();

    // Step 5: block-parallel exclusive prefix scan; write hist (cursor) + starts (pristine)
    {
        const int base = t * (NBINS / 256);
        unsigned int loc[NBINS / 256];
        unsigned int run = 0;
        #pragma unroll
        for (int q = 0; q < NBINS / 256; ++q) { loc[q] = run; run += hist[base + q]; }
        unsigned int inc = run;
        #pragma unroll
        for (int d = 1; d < 64; d <<= 1) {
            unsigned int o = (unsigned int)__shfl_up((int)inc, d);
            if (lane >= d) inc += o;
        }
        if (lane == 63) wred[w] = inc;
        __syncthreads();
        unsigned int woff = 0;
        for (int k = 0; k < 4; ++k) if (k < w) woff += wred[k];
        const unsigned int texcl = woff + inc - run;
        #pragma unroll
        for (int q = 0; q < NBINS / 256; ++q) {
            unsigned int e = texcl + loc[q];
            hist[base + q] = e;
            starts[base + q] = e;
        }
    }
    __syncthreads();

    // Step 6: positional placement — slot = exclusive prefix + arrival order within bucket
    if (has) {
        #pragma unroll
        for (int k = 0; k < 8; ++k) {
            if (starts[bk[k]] < (unsigned int)LL) {
                unsigned int pos = atomicAdd(&hist[bk[k]], 1u);
                if (pos < CANDCAP)
                    cand[pos] = ((unsigned long long)v[k] << 32) | (unsigned int)(8 * t + k);
            }
        }
    }
    __syncthreads();

    // Step 7: intra-bucket insertion sort (runs are tiny; only ~70 buckets qualify)
    for (int b = t; b < NBINS; b += 256) {
        unsigned int s = starts[b];
        if (s < (unsigned int)LL) {
            unsigned int e = hist[b];
            if (e > CANDCAP) e = CANDCAP;
            for (unsigned int i = s + 1; i < e; ++i) {
                unsigned long long key = cand[i];
                int j = (int)i - 1;
                while (j >= (int)s && cand[j] > key) { cand[j + 1] = cand[j]; --j; }
                cand[j + 1] = key;
            }
        }
    }
    __syncthreads();

    // Step 8: emit — slot r IS global rank r on (bits,idx); theta gathered from global
    const float dmax = __uint_as_float((unsigned int)(cand[LL - 1] >> 32));
    float* xrow = xin + (size_t)row * KPAD;
    if (t < LL) {
        unsigned long long key = cand[t];
        unsigned int ij = (unsigned int)key;
        float dv = __uint_as_float((unsigned int)(key >> 32));
        gidx[(size_t)row * LL + t] = (int)ij;
        xrow[t] = dv / dmax;
        xrow[LL + t] = theta[(size_t)row * NN + ij];
    } else if (t == LL) {
        xrow[256] = f0[row];
        xrow[257] = f1[row];
        #pragma unroll
        for (int z = DIN; z < KPAD; ++z) xrow[z] = 0.0f;
    }
}

// ---------------- Kernel C: val = xin @ Wc + bc - dn  (fp32 SGEMM, 128x128 tiles) ----------------
__global__ __launch_bounds__(256) void kC(const float* __restrict__ xin,
                                          const float* __restrict__ Wc,
                                          const float* __restrict__ bc,
                                          float* __restrict__ val) {
    __shared__ __align__(16) float As[8][132];
    __shared__ __align__(16) float Bs[8][128];
    const int t = threadIdx.x;
    const int tr = t >> 4, tc = t & 15;
    const int row0 = blockIdx.x * 128;
    float acc[8][8];
    #pragma unroll
    for (int i = 0; i < 8; ++i)
        #pragma unroll
        for (int j = 0; j < 8; ++j) acc[i][j] = 0.f;

    for (int kc = 0; kc < KPAD; kc += 8) {
        #pragma unroll
        for (int q = 0; q < 4; ++q) {
            int linear = q * 256 + t;
            int m = linear >> 3, k = linear & 7;
            As[k][m] = xin[(size_t)(row0 + m) * KPAD + kc + k];
        }
        #pragma unroll
        for (int q = 0; q < 4; ++q) {
            int linear = q * 256 + t;
            int k = linear >> 7, c = linear & 127;
            Bs[k][c] = Wc[(kc + k) * LL + c];
        }
        __syncthreads();
        #pragma unroll
        for (int k = 0; k < 8; ++k) {
            float a[8], b[8];
            *(float4*)&a[0] = *(const float4*)&As[k][tr * 8];
            *(float4*)&a[4] = *(const float4*)&As[k][tr * 8 + 4];
            *(float4*)&b[0] = *(const float4*)&Bs[k][tc * 8];
            *(float4*)&b[4] = *(const float4*)&Bs[k][tc * 8 + 4];
            #pragma unroll
            for (int i = 0; i < 8; ++i)
                #pragma unroll
                for (int j = 0; j < 8; ++j)
                    acc[i][j] += a[i] * b[j];
        }
        __syncthreads();
    }
    #pragma unroll
    for (int i = 0; i < 8; ++i) {
        int r = row0 + tr * 8 + i;
        #pragma unroll
        for (int j = 0; j < 8; ++j) {
            int c = tc * 8 + j;
            val[(size_t)r * LL + c] = acc[i][j] + bc[c] - xin[(size_t)r * KPAD + c];
        }
    }
}

// ---------------- Kernel D: fill PENALTY row + scatter, stream out ----------------
__global__ __launch_bounds__(256) void kD(const int* __restrict__ gidx,
                                          const float* __restrict__ val,
                                          float* __restrict__ out) {
    __shared__ __align__(16) float rowbuf[NN];
    const int t = threadIdx.x;
    const int row = blockIdx.x;
    for (int i = t; i < NN; i += 256) rowbuf[i] = PENALTY_V;
    __syncthreads();
    if (t < 128) rowbuf[gidx[(size_t)row * LL + t]] = val[(size_t)row * LL + t];
    __syncthreads();
    float4* out4 = (float4*)(out + (size_t)row * NN);
    const float4* rb4 = (const float4*)rowbuf;
    for (int q = t; q < NN / 4; q += 256) out4[q] = rb4[q];
}

extern "C" void kernel_launch(void* const* d_in, const int* in_sizes, int n_in,
                              void* d_out, int out_size, void* d_ws, size_t ws_size,
                              hipStream_t stream) {
    const float* theta = (const float*)d_in[0];
    const float* dist  = (const float*)d_in[1];
    const float* f0    = (const float*)d_in[2];
    const float* f1    = (const float*)d_in[3];
    const float* W1    = (const float*)d_in[4];
    const float* b1    = (const float*)d_in[5];
    const float* W2    = (const float*)d_in[6];
    const float* b2    = (const float*)d_in[7];
    float* out = (float*)d_out;

    char* ws = (char*)d_ws;
    float* Wc   = (float*)ws;                                   // KPAD*128*4 = 135168
    float* bc   = (float*)(ws + 135168);                        // 512
    float* xin  = (float*)(ws + 135680);                        // NROWS*KPAD*4 = 16896000
    int*   gidx = (int*)  (ws + 135680 + 16896000);             // NROWS*128*4 = 8192000
    float* val  = (float*)(ws + 135680 + 16896000 + 8192000);   // NROWS*128*4 = 8192000
    // part aliases val: kA1 writes it, kA2 consumes it, kC later overwrites val.
    float* part = val;                                          // SPLITK*KPAD*128*4 = 2162688 <= 8192000

    kA1<<<33 * SPLITK, 256, 0, stream>>>(W1, b1, W2, part);
    kA2<<<(KPAD * LL) / 256, 256, 0, stream>>>(part, b2, Wc, bc);
    kB<<<NROWS, 256, 0, stream>>>(dist, theta, f0, f1, xin, gidx);
    kC<<<NROWS / 128, 256, 0, stream>>>(xin, Wc, bc, val);
    kD<<<NROWS, 256, 0, stream>>>(gidx, val, out);
}

// Round 5
// 142.373 us; speedup vs baseline: 5.2224x; 1.0266x over previous
//
#include <hip/hip_runtime.h>
#include <hip/hip_bf16.h>

#define BN 8
#define NN 2000
#define LL 128
#define EE 2048
#define DIN 258
#define KPAD 264
#define NROWS (BN*NN)
#define PENALTY_V 10.0f
#define NBINS 1024
#define CANDCAP 256
#define SPLITK 16
#define ECHUNK (EE/SPLITK)   // 128

// ---------------- Kernel A1: partial Wc = W1@W2 over one K-slice ----------------
__global__ __launch_bounds__(256) void kA1(const float* __restrict__ W1,
                                           const float* __restrict__ b1,
                                           const float* __restrict__ W2,
                                           float* __restrict__ part) {
    __shared__ float As2[8][64];
    const int t = threadIdx.x;
    const int j = t & 127;
    const int half = t >> 7;              // 0 or 1
    const int rg = blockIdx.x >> 4;       // row group 0..32
    const int ks = blockIdx.x & 15;       // K slice 0..15
    const int k0 = rg * 8;
    const int ebase = ks * ECHUNK;
    float acc[4] = {0.f, 0.f, 0.f, 0.f};
    for (int ec = ebase; ec < ebase + ECHUNK; ec += 64) {
        #pragma unroll
        for (int q = 0; q < 2; ++q) {
            int linear = q * 256 + t;
            int r8 = linear >> 6;
            int e  = linear & 63;
            int k  = k0 + r8;
            float v;
            if (k < DIN)       v = W1[k * EE + ec + e];
            else if (k == DIN) v = b1[ec + e];
            else               v = 0.0f;
            As2[r8][e] = v;
        }
        __syncthreads();
        #pragma unroll 8
        for (int e = 0; e < 64; ++e) {
            float w = W2[(ec + e) * LL + j];
            #pragma unroll
            for (int rr = 0; rr < 4; ++rr)
                acc[rr] += As2[half * 4 + rr][e] * w;
        }
        __syncthreads();
    }
    #pragma unroll
    for (int rr = 0; rr < 4; ++rr) {
        int k = k0 + half * 4 + rr;       // < KPAD always (max 263)
        part[(size_t)ks * (KPAD * LL) + k * LL + j] = acc[rr];
    }
}

// ---------------- Kernel A2: reduce partials -> Wc, bc ----------------
__global__ __launch_bounds__(256) void kA2(const float* __restrict__ part,
                                           const float* __restrict__ b2,
                                           float* __restrict__ Wc,
                                           float* __restrict__ bc) {
    const int i = blockIdx.x * 256 + threadIdx.x;   // 0..KPAD*LL-1
    float s = 0.f;
    #pragma unroll
    for (int q = 0; q < SPLITK; ++q) s += part[(size_t)q * (KPAD * LL) + i];
    const int k = i >> 7;
    const int j = i & 127;
    if (k == DIN)      { bc[j] = s + b2[j]; Wc[i] = 0.f; }
    else if (k > DIN)  { Wc[i] = 0.f; }
    else               { Wc[i] = s; }
}

// ---- Kernel B: per-row top-128: register-resident, positional placement, parallel rank ----
__global__ __launch_bounds__(256) void kB(const float* __restrict__ dist,
                                          const float* __restrict__ theta,
                                          const float* __restrict__ f0,
                                          const float* __restrict__ f1,
                                          float* __restrict__ xin,
                                          int*   __restrict__ gidx) {
    __shared__ unsigned int hist[NBINS];     // counts -> cursor (end after placement)
    __shared__ unsigned int starts[NBINS];   // pristine exclusive prefix
    __shared__ unsigned long long cand[CANDCAP];
    __shared__ unsigned int wred[4];
    __shared__ float s_od[LL];
    __shared__ int   s_oi[LL];
    __shared__ float s_oth[LL];

    const int t = threadIdx.x;
    const int lane = t & 63;
    const int w = t >> 6;
    const int row = blockIdx.x;

    // Step 1: init hist + cand
    #pragma unroll
    for (int q = 0; q < NBINS / 256; ++q) hist[t + q * 256] = 0u;
    cand[t & (CANDCAP - 1)] = ~0ULL;

    // Step 2: load 8 consecutive elements into registers (thread t owns 8t..8t+7, t<250)
    unsigned int v[8];
    const bool has = (t < 250);
    unsigned int lmax = 0u;
    if (has) {
        const uint4* drow4 = (const uint4*)(dist + (size_t)row * NN);
        uint4 a = drow4[2 * t];
        uint4 b = drow4[2 * t + 1];
        v[0] = a.x; v[1] = a.y; v[2] = a.z; v[3] = a.w;
        v[4] = b.x; v[5] = b.y; v[6] = b.z; v[7] = b.w;
        #pragma unroll
        for (int k = 0; k < 8; ++k) lmax = max(lmax, v[k]);
    }
    #pragma unroll
    for (int d = 32; d > 0; d >>= 1) lmax = max(lmax, (unsigned int)__shfl_down((int)lmax, d));
    if (lane == 0) wred[w] = lmax;
    __syncthreads();   // hist/cand init + wred done

    // Step 3: scale from row max (uint-bit max == float max for positive floats)
    const unsigned int vmax_bits = max(max(wred[0], wred[1]), max(wred[2], wred[3]));
    const float scale = (float)(NBINS - 1) / __uint_as_float(vmax_bits);

    // Step 4: histogram (buckets kept in registers)
    int bk[8];
    if (has) {
        #pragma unroll
        for (int k = 0; k < 8; ++k) {
            float f = __uint_as_float(v[k]);
            int b = (int)(f * scale);
            bk[k] = b < 0 ? 0 : (b > NBINS - 1 ? NBINS - 1 : b);
            atomicAdd(&hist[bk[k]], 1u);
        }
    }
    __syncthreads();

    // Step 5: block-parallel exclusive prefix scan; write hist (cursor) + starts (pristine)
    {
        const int base = t * (NBINS / 256);
        unsigned int loc[NBINS / 256];
        unsigned int run = 0;
        #pragma unroll
        for (int q = 0; q < NBINS / 256; ++q) { loc[q] = run; run += hist[base + q]; }
        unsigned int inc = run;
        #pragma unroll
        for (int d = 1; d < 64; d <<= 1) {
            unsigned int o = (unsigned int)__shfl_up((int)inc, d);
            if (lane >= d) inc += o;
        }
        if (lane == 63) wred[w] = inc;
        __syncthreads();
        unsigned int woff = 0;
        for (int k = 0; k < 4; ++k) if (k < w) woff += wred[k];
        const unsigned int texcl = woff + inc - run;
        #pragma unroll
        for (int q = 0; q < NBINS / 256; ++q) {
            unsigned int e = texcl + loc[q];
            hist[base + q] = e;
            starts[base + q] = e;
        }
    }
    __syncthreads();

    // Step 6: positional placement — slot = exclusive prefix + arrival order within bucket
    if (has) {
        #pragma unroll
        for (int k = 0; k < 8; ++k) {
            if (starts[bk[k]] < (unsigned int)LL) {
                unsigned int pos = atomicAdd(&hist[bk[k]], 1u);
                if (pos < CANDCAP)
                    cand[pos] = ((unsigned long long)v[k] << 32) | (unsigned int)(8 * t + k);
            }
        }
    }
    __syncthreads();

    // Step 7: parallel rank-within-bucket (one thread per slot). Theta load issued
    // before the rank loop so its global latency hides under the LDS reads.
    {
        const unsigned long long key = cand[t];
        if (key != ~0ULL) {
            const unsigned int bits = (unsigned int)(key >> 32);
            const unsigned int idx  = (unsigned int)key;
            const float th = theta[(size_t)row * NN + idx];   // early issue
            float f = __uint_as_float(bits);
            int b = (int)(f * scale);
            b = b < 0 ? 0 : (b > NBINS - 1 ? NBINS - 1 : b);
            unsigned int s = starts[b];
            unsigned int e = hist[b];
            if (e > CANDCAP) e = CANDCAP;
            unsigned int r = s;
            for (unsigned int j = s; j < e; ++j) r += (cand[j] < key);
            if (r < (unsigned int)LL) {
                s_od[r]  = f;
                s_oi[r]  = (int)idx;
                s_oth[r] = th;
            }
        }
    }
    __syncthreads();

    // Step 8: emit
    const float dmax = s_od[LL - 1];
    float* xrow = xin + (size_t)row * KPAD;
    if (t < LL) {
        gidx[(size_t)row * LL + t] = s_oi[t];
        xrow[t] = s_od[t] / dmax;
        xrow[LL + t] = s_oth[t];
    } else if (t == LL) {
        xrow[256] = f0[row];
        xrow[257] = f1[row];
        #pragma unroll
        for (int z = DIN; z < KPAD; ++z) xrow[z] = 0.0f;
    }
}

// ---------------- Kernel C: val = xin @ Wc + bc - dn  (fp32 SGEMM, 128x128 tiles) ----------------
__global__ __launch_bounds__(256) void kC(const float* __restrict__ xin,
                                          const float* __restrict__ Wc,
                                          const float* __restrict__ bc,
                                          float* __restrict__ val) {
    __shared__ __align__(16) float As[8][132];
    __shared__ __align__(16) float Bs[8][128];
    const int t = threadIdx.x;
    const int tr = t >> 4, tc = t & 15;
    const int row0 = blockIdx.x * 128;
    float acc[8][8];
    #pragma unroll
    for (int i = 0; i < 8; ++i)
        #pragma unroll
        for (int j = 0; j < 8; ++j) acc[i][j] = 0.f;

    for (int kc = 0; kc < KPAD; kc += 8) {
        #pragma unroll
        for (int q = 0; q < 4; ++q) {
            int linear = q * 256 + t;
            int m = linear >> 3, k = linear & 7;
            As[k][m] = xin[(size_t)(row0 + m) * KPAD + kc + k];
        }
        #pragma unroll
        for (int q = 0; q < 4; ++q) {
            int linear = q * 256 + t;
            int k = linear >> 7, c = linear & 127;
            Bs[k][c] = Wc[(kc + k) * LL + c];
        }
        __syncthreads();
        #pragma unroll
        for (int k = 0; k < 8; ++k) {
            float a[8], b[8];
            *(float4*)&a[0] = *(const float4*)&As[k][tr * 8];
            *(float4*)&a[4] = *(const float4*)&As[k][tr * 8 + 4];
            *(float4*)&b[0] = *(const float4*)&Bs[k][tc * 8];
            *(float4*)&b[4] = *(const float4*)&Bs[k][tc * 8 + 4];
            #pragma unroll
            for (int i = 0; i < 8; ++i)
                #pragma unroll
                for (int j = 0; j < 8; ++j)
                    acc[i][j] += a[i] * b[j];
        }
        __syncthreads();
    }
    #pragma unroll
    for (int i = 0; i < 8; ++i) {
        int r = row0 + tr * 8 + i;
        #pragma unroll
        for (int j = 0; j < 8; ++j) {
            int c = tc * 8 + j;
            val[(size_t)r * LL + c] = acc[i][j] + bc[c] - xin[(size_t)r * KPAD + c];
        }
    }
}

// ---------------- Kernel D: fill PENALTY row + scatter, stream out ----------------
__global__ __launch_bounds__(256) void kD(const int* __restrict__ gidx,
                                          const float* __restrict__ val,
                                          float* __restrict__ out) {
    __shared__ __align__(16) float rowbuf[NN];
    const int t = threadIdx.x;
    const int row = blockIdx.x;
    for (int i = t; i < NN; i += 256) rowbuf[i] = PENALTY_V;
    __syncthreads();
    if (t < 128) rowbuf[gidx[(size_t)row * LL + t]] = val[(size_t)row * LL + t];
    __syncthreads();
    float4* out4 = (float4*)(out + (size_t)row * NN);
    const float4* rb4 = (const float4*)rowbuf;
    for (int q = t; q < NN / 4; q += 256) out4[q] = rb4[q];
}

extern "C" void kernel_launch(void* const* d_in, const int* in_sizes, int n_in,
                              void* d_out, int out_size, void* d_ws, size_t ws_size,
                              hipStream_t stream) {
    const float* theta = (const float*)d_in[0];
    const float* dist  = (const float*)d_in[1];
    const float* f0    = (const float*)d_in[2];
    const float* f1    = (const float*)d_in[3];
    const float* W1    = (const float*)d_in[4];
    const float* b1    = (const float*)d_in[5];
    const float* W2    = (const float*)d_in[6];
    const float* b2    = (const float*)d_in[7];
    float* out = (float*)d_out;

    char* ws = (char*)d_ws;
    float* Wc   = (float*)ws;                                   // KPAD*128*4 = 135168
    float* bc   = (float*)(ws + 135168);                        // 512
    float* xin  = (float*)(ws + 135680);                        // NROWS*KPAD*4 = 16896000
    int*   gidx = (int*)  (ws + 135680 + 16896000);             // NROWS*128*4 = 8192000
    float* val  = (float*)(ws + 135680 + 16896000 + 8192000);   // NROWS*128*4 = 8192000
    // part aliases val: kA1 writes it, kA2 consumes it, kC later overwrites val.
    float* part = val;                                          // SPLITK*KPAD*128*4 = 2162688 <= 8192000

    kA1<<<33 * SPLITK, 256, 0, stream>>>(W1, b1, W2, part);
    kA2<<<(KPAD * LL) / 256, 256, 0, stream>>>(part, b2, Wc, bc);
    kB<<<NROWS, 256, 0, stream>>>(dist, theta, f0, f1, xin, gidx);
    kC<<<NROWS / 128, 256, 0, stream>>>(xin, Wc, bc, val);
    kD<<<NROWS, 256, 0, stream>>>(gidx, val, out);
}